// Round 3
// baseline (771.748 us; speedup 1.0000x reference)
//
#include <hip/hip_runtime.h>

// ---------------------------------------------------------------------------
// ChatGLM attention block on MI355X (gfx950), bf16 MFMA pipeline.
//   S=2048, B=1, H=4096, NH=32, HD=128, ROT=64.
// Stages: cvt(hs,Wqkv) -> GEMM1(qkv) -> rope(+V transpose) -> attention
//         -> cvt(Wd) -> GEMM2.
// GEMM: 256x256 tile, BK=64, 8 waves, 4-phase/K-tile schedule with counted
// vmcnt (T3+T4), LDS XOR swizzle (T2), setprio around MFMA (T5).
// ---------------------------------------------------------------------------

#define S_LEN 2048
#define NHEAD 32
#define HDIM 128
#define HID 4096

typedef float f32x4 __attribute__((ext_vector_type(4)));
typedef __bf16 bf16x8 __attribute__((ext_vector_type(8)));
typedef __bf16 bf16x4 __attribute__((ext_vector_type(4)));
typedef _Float16 f16x4 __attribute__((ext_vector_type(4)));
typedef _Float16 f16x8 __attribute__((ext_vector_type(8)));

__device__ __forceinline__ void gload16(const void* g, void* l) {
  __builtin_amdgcn_global_load_lds(
      (const __attribute__((address_space(1))) void*)g,
      (__attribute__((address_space(3))) void*)l, 16, 0, 0);
}

// ------------------------- f32 -> bf16 convert ----------------------------
__global__ __launch_bounds__(256) void cvt_f32_bf16_kernel(
    const float* __restrict__ in, __bf16* __restrict__ out, int n4) {
  int i = blockIdx.x * 256 + threadIdx.x;
  if (i >= n4) return;
  f32x4 v = *(const f32x4*)(in + (size_t)i * 4);
  bf16x4 o;
  o[0] = (__bf16)v[0]; o[1] = (__bf16)v[1];
  o[2] = (__bf16)v[2]; o[3] = (__bf16)v[3];
  *(bf16x4*)(out + (size_t)i * 4) = o;
}

// --------------------- 256^2 8-phase GEMM: C = A*B^T + bias ----------------
// Half-tile staging: 128 rows x 64 cols bf16 (128 B/row), 2 gload_lds issues.
// LDS linear; swizzle applied by pre-swizzling the GLOBAL source column and
// applying the same XOR on the ds_read offset (involution, rule #21).
__device__ __forceinline__ void stage_half(const __bf16* __restrict__ G,
                                           int grow0, int K, int kt,
                                           __bf16* lds_half, int tid) {
#pragma unroll
  for (int i = 0; i < 2; ++i) {
    int idx = i * 512 + tid;
    int rr = idx >> 3;
    int offp = (idx & 7) * 16;
    int off = offp ^ ((rr & 7) << 4);
    const char* src = (const char*)(G + (size_t)(grow0 + rr) * K + kt) + off;
    char* dst = (char*)lds_half + idx * 16;
    gload16(src, dst);
  }
}

__device__ __forceinline__ bf16x8 ldsfrag(const __bf16* hb, int rowin, int ks,
                                          int lg) {
  int off = ((ks * 64 + lg * 16) ^ ((rowin & 7) << 4));
  return *(const bf16x8*)((const char*)hb + rowin * 128 + off);
}

// One phase: quadrant (MH,NH); 12 ds_read_b128 -> stage 1 half-tile ->
// barrier -> 16 MFMA (setprio) -> [vmcnt] -> barrier.
#define GPHASE(MH, NH, VMODE, ...)                                             \
  {                                                                            \
    bf16x8 af[4][2], bfr[2][2];                                                \
    _Pragma("unroll") for (int mi = 0; mi < 4; ++mi)                           \
        _Pragma("unroll") for (int ks = 0; ks < 2; ++ks) af[mi][ks] =          \
        ldsfrag(&As[cur][MH][0], wm * 64 + mi * 16 + lr, ks, lg);              \
    _Pragma("unroll") for (int nj = 0; nj < 2; ++nj)                           \
        _Pragma("unroll") for (int ks = 0; ks < 2; ++ks) bfr[nj][ks] =         \
        ldsfrag(&Bs[cur][NH][0], wn * 32 + nj * 16 + lr, ks, lg);              \
    __VA_ARGS__;                                                               \
    asm volatile("s_barrier" ::: "memory");                                    \
    __builtin_amdgcn_s_setprio(1);                                             \
    _Pragma("unroll") for (int mi = 0; mi < 4; ++mi)                           \
        _Pragma("unroll") for (int nj = 0; nj < 2; ++nj)                       \
            _Pragma("unroll") for (int ks = 0; ks < 2; ++ks)                   \
                acc[MH][NH][mi][nj] =                                          \
        __builtin_amdgcn_mfma_f32_16x16x32_bf16(af[mi][ks], bfr[nj][ks],       \
                                                acc[MH][NH][mi][nj], 0, 0, 0); \
    __builtin_amdgcn_s_setprio(0);                                             \
    __builtin_amdgcn_sched_barrier(0);                                         \
    if ((VMODE) == 1) asm volatile("s_waitcnt vmcnt(4)" ::: "memory");         \
    if ((VMODE) == 2) asm volatile("s_waitcnt vmcnt(0)" ::: "memory");         \
    asm volatile("s_barrier" ::: "memory");                                    \
  }

template <int OUT_BF16>
__global__ __launch_bounds__(512, 2) void gemm256_kernel(
    const __bf16* __restrict__ A, const __bf16* __restrict__ B,
    const float* __restrict__ bias, void* __restrict__ Cout, int M, int N,
    int K, int mtiles) {
  __shared__ __align__(16) __bf16 As[2][2][128 * 64];
  __shared__ __align__(16) __bf16 Bs[2][2][128 * 64];
  const int tid = threadIdx.x;
  int bid = blockIdx.x;
  int per_patch = mtiles * 8;
  int p = bid / per_patch, r = bid % per_patch;
  int mt = r % mtiles, nt = p * 8 + r / mtiles;
  int m0 = mt * 256, n0 = nt * 256;
  const int wid = tid >> 6, l = tid & 63;
  const int wm = wid >> 2, wn = wid & 3;
  const int lr = l & 15, lg = l >> 4;
  const int nk = K >> 6;

  f32x4 acc[2][2][4][2];
#pragma unroll
  for (int a = 0; a < 2; ++a)
#pragma unroll
    for (int b = 0; b < 2; ++b)
#pragma unroll
      for (int c = 0; c < 4; ++c)
#pragma unroll
        for (int d = 0; d < 2; ++d) acc[a][b][c][d] = 0.f;

  // Prologue: tile0 all 4 halves + tile1's {A0,B1} -> vmcnt(4) -> barrier.
  stage_half(A, m0, K, 0, &As[0][0][0], tid);
  stage_half(B, n0, K, 0, &Bs[0][0][0], tid);
  stage_half(A, m0 + 128, K, 0, &As[0][1][0], tid);
  stage_half(B, n0 + 128, K, 0, &Bs[0][1][0], tid);
  if (nk > 1) {
    stage_half(A, m0, K, 64, &As[1][0][0], tid);
    stage_half(B, n0 + 128, K, 64, &Bs[1][1][0], tid);
    asm volatile("s_waitcnt vmcnt(4)" ::: "memory");
  } else {
    asm volatile("s_waitcnt vmcnt(0)" ::: "memory");
  }
  asm volatile("s_barrier" ::: "memory");

  // Slot lifetimes per tile (phases p1(0,0) p2(0,1) p3(1,1) p4(1,0)):
  //   A0 dies p2, B1 dies p3, A1/B0 die p4.
  // Stages: p1: A1(t+1)->nxt, p2: B0(t+1)->nxt, p3: A0(t+2)->cur,
  //         p4: B1(t+2)->cur, then vmcnt(4) => tile t+1 fully landed,
  //         {A0,B1}(t+2) stay in flight across the boundary.
  for (int t = 0; t < nk; ++t) {
    const int cur = t & 1, nxt = cur ^ 1;
    const int kt1 = (t + 1) << 6;
    const int kt2 = (t + 2) << 6;
    const bool s1 = (t + 1 < nk), s2 = (t + 2 < nk);
    const int vm4 = s2 ? 1 : 2;
    GPHASE(0, 0, 0,
           if (s1) stage_half(A, m0 + 128, K, kt1, &As[nxt][1][0], tid))
    GPHASE(0, 1, 0, if (s1) stage_half(B, n0, K, kt1, &Bs[nxt][0][0], tid))
    GPHASE(1, 1, 0, if (s2) stage_half(A, m0, K, kt2, &As[cur][0][0], tid))
    GPHASE(1, 0, vm4,
           if (s2) stage_half(B, n0 + 128, K, kt2, &Bs[cur][1][0], tid))
  }

  // Epilogue: C/D layout col=lane&15, row=(lane>>4)*4+j.
#pragma unroll
  for (int mh = 0; mh < 2; ++mh)
#pragma unroll
    for (int nh = 0; nh < 2; ++nh)
#pragma unroll
      for (int mi = 0; mi < 4; ++mi)
#pragma unroll
        for (int nj = 0; nj < 2; ++nj) {
          int row = m0 + mh * 128 + wm * 64 + mi * 16 + lg * 4;
          int col = n0 + nh * 128 + wn * 32 + nj * 16 + lr;
          float bv = bias[col];
          f32x4 v = acc[mh][nh][mi][nj];
#pragma unroll
          for (int j = 0; j < 4; ++j) {
            float o = v[j] + bv;
            if (OUT_BF16)
              ((__bf16*)Cout)[(size_t)(row + j) * N + col] = (__bf16)o;
            else
              ((float*)Cout)[(size_t)(row + j) * N + col] = o;
          }
        }
}

// ------------------------------- RoPE -------------------------------------
// Block = (head h, 64-s chunk). Reads qkv [S][NH*384] bf16.
// Writes Q,K [NH][S][HD] bf16 (Q scaled by 1/sqrt(HD)), VT [NH][HD][S] f16.
__global__ __launch_bounds__(256) void rope_kernel(
    const __bf16* __restrict__ qkv, const int* __restrict__ pos_ids,
    __bf16* __restrict__ Q, __bf16* __restrict__ K, _Float16* __restrict__ VT) {
  int h = blockIdx.x & 31, sb = blockIdx.x >> 5;
  int s0 = sb * 64;
  int t = threadIdx.x;
  __shared__ float cs[64][2][2][32];      // [s_local][half][cos|sin][freq]
  __shared__ _Float16 vs[64][132];        // padded V stage

  for (int idx = t; idx < 64 * 64; idx += 256) {
    int sl = idx >> 6, half = (idx >> 5) & 1, i = idx & 31;
    int p = pos_ids[half * S_LEN + s0 + sl];
    float f = powf(10000.f, -(float)i / 32.f);
    float ang = (float)p * f;
    cs[sl][half][0][i] = cosf(ang);
    cs[sl][half][1][i] = sinf(ang);
  }
#pragma unroll
  for (int c = 0; c < 4; c++) {
    int chunk = c * 256 + t;
    int slv = chunk >> 4, co = (chunk & 15) * 8;
    const __bf16* vsrc =
        qkv + (size_t)(s0 + slv) * (NHEAD * 3 * HDIM) + h * 384 + 256 + co;
    bf16x8 vv = *(const bf16x8*)vsrc;
    f16x4 a, b;
#pragma unroll
    for (int j = 0; j < 4; j++) {
      a[j] = (_Float16)(float)vv[j];
      b[j] = (_Float16)(float)vv[4 + j];
    }
    *(f16x4*)&vs[slv][co] = a;
    *(f16x4*)&vs[slv][co + 4] = b;
  }
  __syncthreads();

  {
    int sl = t >> 2, role = t & 3;
    int isK = role >> 1, half = role & 1;
    const __bf16* src = qkv + (size_t)(s0 + sl) * (NHEAD * 3 * HDIM) + h * 384 +
                        isK * 128 + half * 64;
    float scale = isK ? 1.f : 0.08838834764831845f;  // 1/sqrt(128)
    float x[64];
    bf16x8 buf[8];
#pragma unroll
    for (int c = 0; c < 8; c++) buf[c] = *(const bf16x8*)(src + c * 8);
#pragma unroll
    for (int c = 0; c < 8; c++)
#pragma unroll
      for (int j = 0; j < 8; j++) x[c * 8 + j] = (float)buf[c][j];
    bf16x8 ob[8];
#pragma unroll
    for (int i = 0; i < 64; i++) {
      int ii = i & 31;
      float cv = cs[sl][half][0][ii], sv = cs[sl][half][1][ii];
      float partner = (i < 32) ? x[i + 32] : x[i - 32];
      float sgn = (i < 32) ? -1.f : 1.f;
      float o = (x[i] * cv + sgn * partner * sv) * scale;
      ob[i >> 3][i & 7] = (__bf16)o;
    }
    __bf16* dst = (isK ? K : Q) + ((size_t)h * S_LEN + s0 + sl) * HDIM + half * 64;
#pragma unroll
    for (int c = 0; c < 8; c++) *(bf16x8*)(dst + c * 8) = ob[c];
  }

#pragma unroll
  for (int c = 0; c < 4; c++) {
    int chunk = c * 256 + t;
    int d = chunk >> 3, so = (chunk & 7) * 8;
    f16x8 o;
#pragma unroll
    for (int j = 0; j < 8; j++) o[j] = vs[so + j][d];
    *(f16x8*)(VT + ((size_t)h * HDIM + d) * S_LEN + s0 + so) = o;
  }
}

// ---------------------------- Flash attention ------------------------------
__global__ __launch_bounds__(256, 2) void attn_kernel(
    const __bf16* __restrict__ Q, const __bf16* __restrict__ K,
    const _Float16* __restrict__ VT, __bf16* __restrict__ ctx) {
  int b = blockIdx.x;
  int h = b & 31;
  int qb = 15 - (b >> 5);
  int w = threadIdx.x >> 6, l = threadIdx.x & 63;
  int lr = l & 15, lg = l >> 4;
  int q0 = qb * 128 + w * 32;
  const __bf16* Qh = Q + (size_t)h * S_LEN * HDIM;
  const __bf16* Kh = K + (size_t)h * S_LEN * HDIM;
  const _Float16* Vh = VT + (size_t)h * HDIM * S_LEN;

  bf16x8 qfA[4], qfB[4];
#pragma unroll
  for (int kk = 0; kk < 4; kk++) {
    qfA[kk] = *(const bf16x8*)(Qh + (size_t)(q0 + lr) * HDIM + kk * 32 + lg * 8);
    qfB[kk] =
        *(const bf16x8*)(Qh + (size_t)(q0 + 16 + lr) * HDIM + kk * 32 + lg * 8);
  }

  f32x4 accA[8], accB[8];
#pragma unroll
  for (int tt = 0; tt < 8; tt++) { accA[tt] = 0.f; accB[tt] = 0.f; }
  float mA = -INFINITY, lsA = 0.f, mB = -INFINITY, lsB = 0.f;
  int qgA = q0 + lr, qgB = q0 + 16 + lr;
  int qmax = q0 + 31;

  for (int kv0 = 0; kv0 <= qmax; kv0 += 16) {
    f32x4 stA = 0.f, stB = 0.f;
#pragma unroll
    for (int kk = 0; kk < 4; kk++) {
      bf16x8 kf =
          *(const bf16x8*)(Kh + (size_t)(kv0 + lr) * HDIM + kk * 32 + lg * 8);
      stA = __builtin_amdgcn_mfma_f32_16x16x32_bf16(kf, qfA[kk], stA, 0, 0, 0);
      stB = __builtin_amdgcn_mfma_f32_16x16x32_bf16(kf, qfB[kk], stB, 0, 0, 0);
    }
    float tmA = -INFINITY, tmB = -INFINITY;
#pragma unroll
    for (int j = 0; j < 4; j++) {
      int kvg = kv0 + lg * 4 + j;
      if (kvg > qgA) stA[j] = -INFINITY;
      if (kvg > qgB) stB[j] = -INFINITY;
      tmA = fmaxf(tmA, stA[j]);
      tmB = fmaxf(tmB, stB[j]);
    }
    tmA = fmaxf(tmA, __shfl_xor(tmA, 16));
    tmA = fmaxf(tmA, __shfl_xor(tmA, 32));
    tmB = fmaxf(tmB, __shfl_xor(tmB, 16));
    tmB = fmaxf(tmB, __shfl_xor(tmB, 32));
    int need = __any((tmA > mA) || (tmB > mB));
    float mnA = fmaxf(mA, tmA), mnB = fmaxf(mB, tmB);

    f16x4 paA, paB;
    float tsA = 0.f, tsB = 0.f;
#pragma unroll
    for (int j = 0; j < 4; j++) {
      float pA = __expf(stA[j] - mnA);
      float pB = __expf(stB[j] - mnB);
      tsA += pA; tsB += pB;
      paA[j] = (_Float16)pA; paB[j] = (_Float16)pB;
    }
    tsA += __shfl_xor(tsA, 16);
    tsA += __shfl_xor(tsA, 32);
    tsB += __shfl_xor(tsB, 16);
    tsB += __shfl_xor(tsB, 32);

    if (need) {
      float scA = __expf(mA - mnA), scB = __expf(mB - mnB);
      lsA = lsA * scA + tsA;
      lsB = lsB * scB + tsB;
      float sAj[4], sBj[4];
#pragma unroll
      for (int j = 0; j < 4; j++) {
        sAj[j] = __shfl(scA, lg * 4 + j);
        sBj[j] = __shfl(scB, lg * 4 + j);
      }
#pragma unroll
      for (int tt = 0; tt < 8; tt++)
#pragma unroll
        for (int j = 0; j < 4; j++) {
          accA[tt][j] *= sAj[j];
          accB[tt][j] *= sBj[j];
        }
    } else {
      lsA += tsA;
      lsB += tsB;
    }
    mA = mnA; mB = mnB;

#pragma unroll
    for (int tt = 0; tt < 8; tt++) {
      f16x4 vb =
          *(const f16x4*)(Vh + (size_t)(tt * 16 + lr) * S_LEN + kv0 + lg * 4);
      accA[tt] = __builtin_amdgcn_mfma_f32_16x16x16f16(paA, vb, accA[tt], 0, 0, 0);
      accB[tt] = __builtin_amdgcn_mfma_f32_16x16x16f16(paB, vb, accB[tt], 0, 0, 0);
    }
  }

  float rA[4], rB[4];
#pragma unroll
  for (int j = 0; j < 4; j++) {
    rA[j] = 1.f / __shfl(lsA, lg * 4 + j);
    rB[j] = 1.f / __shfl(lsB, lg * 4 + j);
  }
#pragma unroll
  for (int tt = 0; tt < 8; tt++) {
#pragma unroll
    for (int j = 0; j < 4; j++) {
      int qoA = q0 + lg * 4 + j;
      int qoB = q0 + 16 + lg * 4 + j;
      ctx[(size_t)qoA * (NHEAD * HDIM) + h * HDIM + tt * 16 + lr] =
          (__bf16)(accA[tt][j] * rA[j]);
      ctx[(size_t)qoB * (NHEAD * HDIM) + h * HDIM + tt * 16 + lr] =
          (__bf16)(accB[tt][j] * rB[j]);
    }
  }
}

// ---------------------------------------------------------------------------
extern "C" void kernel_launch(void* const* d_in, const int* in_sizes, int n_in,
                              void* d_out, int out_size, void* d_ws,
                              size_t ws_size, hipStream_t stream) {
  const float* hs = (const float*)d_in[0];
  const int* pos_ids = (const int*)d_in[1];
  const float* Wqkv = (const float*)d_in[4];
  const float* bqkv = (const float*)d_in[5];
  const float* Wd = (const float*)d_in[6];
  const float* bd = (const float*)d_in[7];
  float* out = (float*)d_out;

  char* ws = (char*)d_ws;
  constexpr size_t OFF_W = 16777216ULL;
  constexpr size_t OFF_QKV = OFF_W + 100663296ULL;
  constexpr size_t OFF_Q = OFF_QKV + 50331648ULL;
  constexpr size_t OFF_K = OFF_Q + 16777216ULL;
  constexpr size_t OFF_V = OFF_K + 16777216ULL;
  __bf16* hsb = (__bf16*)(ws);
  __bf16* wqkvb = (__bf16*)(ws + OFF_W);
  __bf16* wdb = (__bf16*)(ws + OFF_W);  // aliases wqkvb (used after GEMM1)
  __bf16* qkvb = (__bf16*)(ws + OFF_QKV);
  __bf16* ctxb = qkvb;                  // aliases qkv (used after rope)
  __bf16* Qb = (__bf16*)(ws + OFF_Q);
  __bf16* Kb = (__bf16*)(ws + OFF_K);
  _Float16* Vtb = (_Float16*)(ws + OFF_V);

  cvt_f32_bf16_kernel<<<(S_LEN * HID) / 4 / 256, 256, 0, stream>>>(
      hs, hsb, S_LEN * HID / 4);
  cvt_f32_bf16_kernel<<<(3 * HID * HID) / 4 / 256, 256, 0, stream>>>(
      Wqkv, wqkvb, 3 * HID * HID / 4);

  // GEMM1: [2048,4096] x [12288,4096]^T -> bf16 qkv. 8x48 tiles of 256^2.
  gemm256_kernel<1><<<8 * 48, 512, 0, stream>>>(hsb, wqkvb, bqkv, qkvb, S_LEN,
                                                3 * HID, HID, 8);

  cvt_f32_bf16_kernel<<<(HID * HID) / 4 / 256, 256, 0, stream>>>(
      Wd, wdb, HID * HID / 4);

  rope_kernel<<<NHEAD * (S_LEN / 64), 256, 0, stream>>>(qkvb, pos_ids, Qb, Kb,
                                                        Vtb);

  attn_kernel<<<NHEAD * (S_LEN / 128), 256, 0, stream>>>(Qb, Kb, Vtb, ctxb);

  // GEMM2: [2048,4096] x [4096,4096]^T + bd -> f32 out. 8x16 tiles.
  gemm256_kernel<0><<<8 * 16, 512, 0, stream>>>(ctxb, wdb, bd, out, S_LEN,
                                                HID, HID, 8);
}

// Round 4
// 683.701 us; speedup vs baseline: 1.1288x; 1.1288x over previous
//
#include <hip/hip_runtime.h>

// ---------------------------------------------------------------------------
// ChatGLM attention block on MI355X (gfx950), bf16 MFMA pipeline.
//   S=2048, B=1, H=4096, NH=32, HD=128, ROT=64.
// Stages: cvt(hs,Wqkv) -> GEMM1(qkv) -> rope(+V transpose) -> attention
//         -> cvt(Wd) -> GEMM2(split-K2) -> reduce+bias.
// GEMM: 256x256 tile, BK=64, 8 waves, 4-phase/K-tile with fragment carry
// (24 ds_read_b128 per K-tile instead of 48), counted vmcnt(8), T2 swizzle,
// T5 setprio.
// ---------------------------------------------------------------------------

#define S_LEN 2048
#define NHEAD 32
#define HDIM 128
#define HID 4096

typedef float f32x4 __attribute__((ext_vector_type(4)));
typedef __bf16 bf16x8 __attribute__((ext_vector_type(8)));
typedef __bf16 bf16x4 __attribute__((ext_vector_type(4)));
typedef _Float16 f16x4 __attribute__((ext_vector_type(4)));
typedef _Float16 f16x8 __attribute__((ext_vector_type(8)));

__device__ __forceinline__ void gload16(const void* g, void* l) {
  __builtin_amdgcn_global_load_lds(
      (const __attribute__((address_space(1))) void*)g,
      (__attribute__((address_space(3))) void*)l, 16, 0, 0);
}

// ------------------------- f32 -> bf16 convert ----------------------------
__global__ __launch_bounds__(256) void cvt_f32_bf16_kernel(
    const float* __restrict__ in, __bf16* __restrict__ out, int n4) {
  int i = blockIdx.x * 256 + threadIdx.x;
  if (i >= n4) return;
  f32x4 v = *(const f32x4*)(in + (size_t)i * 4);
  bf16x4 o;
  o[0] = (__bf16)v[0]; o[1] = (__bf16)v[1];
  o[2] = (__bf16)v[2]; o[3] = (__bf16)v[3];
  *(bf16x4*)(out + (size_t)i * 4) = o;
}

// --------------------- 256^2 GEMM: C = A*B^T (+ bias) ----------------------
// OUT_MODE: 0 = f32 + bias, 1 = bf16 + bias, 2 = f32 partial (no bias,
// output offset kh*M*N for split-K).
__device__ __forceinline__ void stage_half(const __bf16* __restrict__ G,
                                           int grow0, int Kstride, int kofs,
                                           __bf16* lds_half, int tid) {
#pragma unroll
  for (int i = 0; i < 2; ++i) {
    int idx = i * 512 + tid;
    int rr = idx >> 3;
    int offp = (idx & 7) * 16;
    int off = offp ^ ((rr & 7) << 4);
    const char* src =
        (const char*)(G + (size_t)(grow0 + rr) * Kstride + kofs) + off;
    char* dst = (char*)lds_half + idx * 16;
    gload16(src, dst);
  }
}

__device__ __forceinline__ bf16x8 ldsfrag(const __bf16* hb, int rowin, int ks,
                                          int lg) {
  int off = ((ks * 64 + lg * 16) ^ ((rowin & 7) << 4));
  return *(const bf16x8*)((const char*)hb + rowin * 128 + off);
}

template <int OUT_MODE>
__global__ __launch_bounds__(512, 2) void gemm256_kernel(
    const __bf16* __restrict__ A, const __bf16* __restrict__ B,
    const float* __restrict__ bias, void* __restrict__ Cout, int M, int N,
    int Kstride, int klen, int mtiles, int ksplit) {
  __shared__ __align__(16) __bf16 As[2][2][128 * 64];
  __shared__ __align__(16) __bf16 Bs[2][2][128 * 64];
  const int tid = threadIdx.x;
  int bid = blockIdx.x;
  int kh = 0;
  if (ksplit == 2) { kh = bid & 1; bid >>= 1; }
  const int kbase = kh * klen;
  int per_patch = mtiles * 8;
  int p = bid / per_patch, r = bid % per_patch;
  int mt = r % mtiles, nt = p * 8 + r / mtiles;
  int m0 = mt * 256, n0 = nt * 256;
  const int wid = tid >> 6, l = tid & 63;
  const int wm = wid >> 2, wn = wid & 3;
  const int lr = l & 15, lg = l >> 4;
  const int nk = klen >> 6;

  f32x4 acc[2][2][4][2];
#pragma unroll
  for (int a = 0; a < 2; ++a)
#pragma unroll
    for (int b = 0; b < 2; ++b)
#pragma unroll
      for (int c = 0; c < 4; ++c)
#pragma unroll
        for (int d = 0; d < 2; ++d) acc[a][b][c][d] = 0.f;

  // Prologue: tile0 (8 loads) + tile1 (8 loads); drain tile0, keep t1 in
  // flight (8 outstanding).
  stage_half(A, m0, Kstride, kbase, &As[0][0][0], tid);
  stage_half(A, m0 + 128, Kstride, kbase, &As[0][1][0], tid);
  stage_half(B, n0, Kstride, kbase, &Bs[0][0][0], tid);
  stage_half(B, n0 + 128, Kstride, kbase, &Bs[0][1][0], tid);
  if (nk > 1) {
    stage_half(A, m0, Kstride, kbase + 64, &As[1][0][0], tid);
    stage_half(B, n0, Kstride, kbase + 64, &Bs[1][0][0], tid);
    stage_half(B, n0 + 128, Kstride, kbase + 64, &Bs[1][1][0], tid);
    stage_half(A, m0 + 128, Kstride, kbase + 64, &As[1][1][0], tid);
    asm volatile("s_waitcnt vmcnt(8)" ::: "memory");
  } else {
    asm volatile("s_waitcnt vmcnt(0)" ::: "memory");
  }
  asm volatile("s_barrier" ::: "memory");

  // 4 phases per K-tile, fragment carry:
  //   p1 Q(0,0): read A0(8)+B0(4)                          [A0,B0 LDS-dead]
  //   p2 Q(0,1): read B1(4); stage A0,B0(t+2)->cur         [B1 LDS-dead]
  //   p3 Q(1,1): read A1(8); stage B1(t+2)->cur            [A1 LDS-dead]
  //   p4 Q(1,0): (all carried); stage A1(t+2)->cur; vmcnt(8)
  // Tile t+2 lands in cur slots as they die; nxt (tile t+1) untouched.
  // vmcnt(8) drains tile-(t+1) loads issued 4-6 phases earlier.
  for (int t = 0; t < nk; ++t) {
    const int cur = t & 1;
    const int kt2 = kbase + ((t + 2) << 6);
    const bool s2 = (t + 2 < nk);
    bf16x8 a[4][2], b0[2][2], b1[2][2];

    // ---- p1: Q(0,0) ----
#pragma unroll
    for (int mi = 0; mi < 4; ++mi)
#pragma unroll
      for (int ks = 0; ks < 2; ++ks)
        a[mi][ks] = ldsfrag(&As[cur][0][0], wm * 64 + mi * 16 + lr, ks, lg);
#pragma unroll
    for (int nj = 0; nj < 2; ++nj)
#pragma unroll
      for (int ks = 0; ks < 2; ++ks)
        b0[nj][ks] = ldsfrag(&Bs[cur][0][0], wn * 32 + nj * 16 + lr, ks, lg);
    __builtin_amdgcn_s_setprio(1);
#pragma unroll
    for (int mi = 0; mi < 4; ++mi)
#pragma unroll
      for (int nj = 0; nj < 2; ++nj)
#pragma unroll
        for (int ks = 0; ks < 2; ++ks)
          acc[0][0][mi][nj] = __builtin_amdgcn_mfma_f32_16x16x32_bf16(
              a[mi][ks], b0[nj][ks], acc[0][0][mi][nj], 0, 0, 0);
    __builtin_amdgcn_s_setprio(0);
    asm volatile("s_barrier" ::: "memory");

    // ---- p2: Q(0,1) ----
#pragma unroll
    for (int nj = 0; nj < 2; ++nj)
#pragma unroll
      for (int ks = 0; ks < 2; ++ks)
        b1[nj][ks] = ldsfrag(&Bs[cur][1][0], wn * 32 + nj * 16 + lr, ks, lg);
    if (s2) {
      stage_half(A, m0, Kstride, kt2, &As[cur][0][0], tid);
      stage_half(B, n0, Kstride, kt2, &Bs[cur][0][0], tid);
    }
    __builtin_amdgcn_s_setprio(1);
#pragma unroll
    for (int mi = 0; mi < 4; ++mi)
#pragma unroll
      for (int nj = 0; nj < 2; ++nj)
#pragma unroll
        for (int ks = 0; ks < 2; ++ks)
          acc[0][1][mi][nj] = __builtin_amdgcn_mfma_f32_16x16x32_bf16(
              a[mi][ks], b1[nj][ks], acc[0][1][mi][nj], 0, 0, 0);
    __builtin_amdgcn_s_setprio(0);
    asm volatile("s_barrier" ::: "memory");

    // ---- p3: Q(1,1) ----
#pragma unroll
    for (int mi = 0; mi < 4; ++mi)
#pragma unroll
      for (int ks = 0; ks < 2; ++ks)
        a[mi][ks] = ldsfrag(&As[cur][1][0], wm * 64 + mi * 16 + lr, ks, lg);
    if (s2) stage_half(B, n0 + 128, Kstride, kt2, &Bs[cur][1][0], tid);
    __builtin_amdgcn_s_setprio(1);
#pragma unroll
    for (int mi = 0; mi < 4; ++mi)
#pragma unroll
      for (int nj = 0; nj < 2; ++nj)
#pragma unroll
        for (int ks = 0; ks < 2; ++ks)
          acc[1][1][mi][nj] = __builtin_amdgcn_mfma_f32_16x16x32_bf16(
              a[mi][ks], b1[nj][ks], acc[1][1][mi][nj], 0, 0, 0);
    __builtin_amdgcn_s_setprio(0);
    asm volatile("s_barrier" ::: "memory");

    // ---- p4: Q(1,0) ----
    if (s2) stage_half(A, m0 + 128, Kstride, kt2, &As[cur][1][0], tid);
    __builtin_amdgcn_s_setprio(1);
#pragma unroll
    for (int mi = 0; mi < 4; ++mi)
#pragma unroll
      for (int nj = 0; nj < 2; ++nj)
#pragma unroll
        for (int ks = 0; ks < 2; ++ks)
          acc[1][0][mi][nj] = __builtin_amdgcn_mfma_f32_16x16x32_bf16(
              a[mi][ks], b0[nj][ks], acc[1][0][mi][nj], 0, 0, 0);
    __builtin_amdgcn_s_setprio(0);
    if (s2)
      asm volatile("s_waitcnt vmcnt(8)" ::: "memory");
    else
      asm volatile("s_waitcnt vmcnt(0)" ::: "memory");
    asm volatile("s_barrier" ::: "memory");
  }

  // Epilogue: C/D layout col=lane&15, row=(lane>>4)*4+j.
  float* outF = (float*)Cout;
  if (OUT_MODE == 2) outF += (size_t)kh * M * N;
#pragma unroll
  for (int mh = 0; mh < 2; ++mh)
#pragma unroll
    for (int nh = 0; nh < 2; ++nh)
#pragma unroll
      for (int mi = 0; mi < 4; ++mi)
#pragma unroll
        for (int nj = 0; nj < 2; ++nj) {
          int row = m0 + mh * 128 + wm * 64 + mi * 16 + lg * 4;
          int col = n0 + nh * 128 + wn * 32 + nj * 16 + lr;
          float bv = (OUT_MODE == 2) ? 0.f : bias[col];
          f32x4 v = acc[mh][nh][mi][nj];
#pragma unroll
          for (int j = 0; j < 4; ++j) {
            float o = v[j] + bv;
            if (OUT_MODE == 1)
              ((__bf16*)Cout)[(size_t)(row + j) * N + col] = (__bf16)o;
            else
              outF[(size_t)(row + j) * N + col] = o;
          }
        }
}

// ---------------- split-K reduce: out = p0 + p1 + bias ---------------------
__global__ __launch_bounds__(256) void reduce_addbias_kernel(
    const float* __restrict__ p0, const float* __restrict__ p1,
    const float* __restrict__ bias, float* __restrict__ out) {
  int i = blockIdx.x * 256 + threadIdx.x;  // i indexes f32x4 chunks
  int col = (i * 4) & (HID - 1);
  f32x4 a = *(const f32x4*)(p0 + (size_t)i * 4);
  f32x4 b = *(const f32x4*)(p1 + (size_t)i * 4);
  f32x4 c = *(const f32x4*)(bias + col);
  a = a + b + c;
  *(f32x4*)(out + (size_t)i * 4) = a;
}

// ------------------------------- RoPE -------------------------------------
// Block = (head h, 64-s chunk). Reads qkv [S][NH*384] bf16.
// Writes Q,K [NH][S][HD] bf16 (Q scaled by 1/sqrt(HD)), VT [NH][HD][S] f16.
__global__ __launch_bounds__(256) void rope_kernel(
    const __bf16* __restrict__ qkv, const int* __restrict__ pos_ids,
    __bf16* __restrict__ Q, __bf16* __restrict__ K, _Float16* __restrict__ VT) {
  int h = blockIdx.x & 31, sb = blockIdx.x >> 5;
  int s0 = sb * 64;
  int t = threadIdx.x;
  __shared__ float cs[64][2][2][32];
  __shared__ _Float16 vs[64][132];

  for (int idx = t; idx < 64 * 64; idx += 256) {
    int sl = idx >> 6, half = (idx >> 5) & 1, i = idx & 31;
    int p = pos_ids[half * S_LEN + s0 + sl];
    float f = powf(10000.f, -(float)i / 32.f);
    float ang = (float)p * f;
    cs[sl][half][0][i] = cosf(ang);
    cs[sl][half][1][i] = sinf(ang);
  }
#pragma unroll
  for (int c = 0; c < 4; c++) {
    int chunk = c * 256 + t;
    int slv = chunk >> 4, co = (chunk & 15) * 8;
    const __bf16* vsrc =
        qkv + (size_t)(s0 + slv) * (NHEAD * 3 * HDIM) + h * 384 + 256 + co;
    bf16x8 vv = *(const bf16x8*)vsrc;
    f16x4 a, b;
#pragma unroll
    for (int j = 0; j < 4; j++) {
      a[j] = (_Float16)(float)vv[j];
      b[j] = (_Float16)(float)vv[4 + j];
    }
    *(f16x4*)&vs[slv][co] = a;
    *(f16x4*)&vs[slv][co + 4] = b;
  }
  __syncthreads();

  {
    int sl = t >> 2, role = t & 3;
    int isK = role >> 1, half = role & 1;
    const __bf16* src = qkv + (size_t)(s0 + sl) * (NHEAD * 3 * HDIM) + h * 384 +
                        isK * 128 + half * 64;
    float scale = isK ? 1.f : 0.08838834764831845f;  // 1/sqrt(128)
    float x[64];
    bf16x8 buf[8];
#pragma unroll
    for (int c = 0; c < 8; c++) buf[c] = *(const bf16x8*)(src + c * 8);
#pragma unroll
    for (int c = 0; c < 8; c++)
#pragma unroll
      for (int j = 0; j < 8; j++) x[c * 8 + j] = (float)buf[c][j];
    bf16x8 ob[8];
#pragma unroll
    for (int i = 0; i < 64; i++) {
      int ii = i & 31;
      float cv = cs[sl][half][0][ii], sv = cs[sl][half][1][ii];
      float partner = (i < 32) ? x[i + 32] : x[i - 32];
      float sgn = (i < 32) ? -1.f : 1.f;
      float o = (x[i] * cv + sgn * partner * sv) * scale;
      ob[i >> 3][i & 7] = (__bf16)o;
    }
    __bf16* dst = (isK ? K : Q) + ((size_t)h * S_LEN + s0 + sl) * HDIM + half * 64;
#pragma unroll
    for (int c = 0; c < 8; c++) *(bf16x8*)(dst + c * 8) = ob[c];
  }

#pragma unroll
  for (int c = 0; c < 4; c++) {
    int chunk = c * 256 + t;
    int d = chunk >> 3, so = (chunk & 7) * 8;
    f16x8 o;
#pragma unroll
    for (int j = 0; j < 8; j++) o[j] = vs[so + j][d];
    *(f16x8*)(VT + ((size_t)h * HDIM + d) * S_LEN + s0 + so) = o;
  }
}

// ---------------------------- Flash attention ------------------------------
__global__ __launch_bounds__(256, 2) void attn_kernel(
    const __bf16* __restrict__ Q, const __bf16* __restrict__ K,
    const _Float16* __restrict__ VT, __bf16* __restrict__ ctx) {
  int b = blockIdx.x;
  int h = b & 31;
  int qb = 15 - (b >> 5);
  int w = threadIdx.x >> 6, l = threadIdx.x & 63;
  int lr = l & 15, lg = l >> 4;
  int q0 = qb * 128 + w * 32;
  const __bf16* Qh = Q + (size_t)h * S_LEN * HDIM;
  const __bf16* Kh = K + (size_t)h * S_LEN * HDIM;
  const _Float16* Vh = VT + (size_t)h * HDIM * S_LEN;

  bf16x8 qfA[4], qfB[4];
#pragma unroll
  for (int kk = 0; kk < 4; kk++) {
    qfA[kk] = *(const bf16x8*)(Qh + (size_t)(q0 + lr) * HDIM + kk * 32 + lg * 8);
    qfB[kk] =
        *(const bf16x8*)(Qh + (size_t)(q0 + 16 + lr) * HDIM + kk * 32 + lg * 8);
  }

  f32x4 accA[8], accB[8];
#pragma unroll
  for (int tt = 0; tt < 8; tt++) { accA[tt] = 0.f; accB[tt] = 0.f; }
  float mA = -INFINITY, lsA = 0.f, mB = -INFINITY, lsB = 0.f;
  int qgA = q0 + lr, qgB = q0 + 16 + lr;
  int qmax = q0 + 31;

  for (int kv0 = 0; kv0 <= qmax; kv0 += 16) {
    f32x4 stA = 0.f, stB = 0.f;
#pragma unroll
    for (int kk = 0; kk < 4; kk++) {
      bf16x8 kf =
          *(const bf16x8*)(Kh + (size_t)(kv0 + lr) * HDIM + kk * 32 + lg * 8);
      stA = __builtin_amdgcn_mfma_f32_16x16x32_bf16(kf, qfA[kk], stA, 0, 0, 0);
      stB = __builtin_amdgcn_mfma_f32_16x16x32_bf16(kf, qfB[kk], stB, 0, 0, 0);
    }
    float tmA = -INFINITY, tmB = -INFINITY;
#pragma unroll
    for (int j = 0; j < 4; j++) {
      int kvg = kv0 + lg * 4 + j;
      if (kvg > qgA) stA[j] = -INFINITY;
      if (kvg > qgB) stB[j] = -INFINITY;
      tmA = fmaxf(tmA, stA[j]);
      tmB = fmaxf(tmB, stB[j]);
    }
    tmA = fmaxf(tmA, __shfl_xor(tmA, 16));
    tmA = fmaxf(tmA, __shfl_xor(tmA, 32));
    tmB = fmaxf(tmB, __shfl_xor(tmB, 16));
    tmB = fmaxf(tmB, __shfl_xor(tmB, 32));
    int need = __any((tmA > mA) || (tmB > mB));
    float mnA = fmaxf(mA, tmA), mnB = fmaxf(mB, tmB);

    f16x4 paA, paB;
    float tsA = 0.f, tsB = 0.f;
#pragma unroll
    for (int j = 0; j < 4; j++) {
      float pA = __expf(stA[j] - mnA);
      float pB = __expf(stB[j] - mnB);
      tsA += pA; tsB += pB;
      paA[j] = (_Float16)pA; paB[j] = (_Float16)pB;
    }
    tsA += __shfl_xor(tsA, 16);
    tsA += __shfl_xor(tsA, 32);
    tsB += __shfl_xor(tsB, 16);
    tsB += __shfl_xor(tsB, 32);

    if (need) {
      float scA = __expf(mA - mnA), scB = __expf(mB - mnB);
      lsA = lsA * scA + tsA;
      lsB = lsB * scB + tsB;
      float sAj[4], sBj[4];
#pragma unroll
      for (int j = 0; j < 4; j++) {
        sAj[j] = __shfl(scA, lg * 4 + j);
        sBj[j] = __shfl(scB, lg * 4 + j);
      }
#pragma unroll
      for (int tt = 0; tt < 8; tt++)
#pragma unroll
        for (int j = 0; j < 4; j++) {
          accA[tt][j] *= sAj[j];
          accB[tt][j] *= sBj[j];
        }
    } else {
      lsA += tsA;
      lsB += tsB;
    }
    mA = mnA; mB = mnB;

#pragma unroll
    for (int tt = 0; tt < 8; tt++) {
      f16x4 vb =
          *(const f16x4*)(Vh + (size_t)(tt * 16 + lr) * S_LEN + kv0 + lg * 4);
      accA[tt] = __builtin_amdgcn_mfma_f32_16x16x16f16(paA, vb, accA[tt], 0, 0, 0);
      accB[tt] = __builtin_amdgcn_mfma_f32_16x16x16f16(paB, vb, accB[tt], 0, 0, 0);
    }
  }

  float rA[4], rB[4];
#pragma unroll
  for (int j = 0; j < 4; j++) {
    rA[j] = 1.f / __shfl(lsA, lg * 4 + j);
    rB[j] = 1.f / __shfl(lsB, lg * 4 + j);
  }
#pragma unroll
  for (int tt = 0; tt < 8; tt++) {
#pragma unroll
    for (int j = 0; j < 4; j++) {
      int qoA = q0 + lg * 4 + j;
      int qoB = q0 + 16 + lg * 4 + j;
      ctx[(size_t)qoA * (NHEAD * HDIM) + h * HDIM + tt * 16 + lr] =
          (__bf16)(accA[tt][j] * rA[j]);
      ctx[(size_t)qoB * (NHEAD * HDIM) + h * HDIM + tt * 16 + lr] =
          (__bf16)(accB[tt][j] * rB[j]);
    }
  }
}

// ---------------------------------------------------------------------------
extern "C" void kernel_launch(void* const* d_in, const int* in_sizes, int n_in,
                              void* d_out, int out_size, void* d_ws,
                              size_t ws_size, hipStream_t stream) {
  const float* hs = (const float*)d_in[0];
  const int* pos_ids = (const int*)d_in[1];
  const float* Wqkv = (const float*)d_in[4];
  const float* bqkv = (const float*)d_in[5];
  const float* Wd = (const float*)d_in[6];
  const float* bd = (const float*)d_in[7];
  float* out = (float*)d_out;

  char* ws = (char*)d_ws;
  constexpr size_t OFF_W = 16777216ULL;
  constexpr size_t OFF_QKV = OFF_W + 100663296ULL;
  constexpr size_t OFF_Q = OFF_QKV + 50331648ULL;
  constexpr size_t OFF_K = OFF_Q + 16777216ULL;
  constexpr size_t OFF_V = OFF_K + 16777216ULL;
  __bf16* hsb = (__bf16*)(ws);
  __bf16* wqkvb = (__bf16*)(ws + OFF_W);
  __bf16* wdb = (__bf16*)(ws + OFF_W);  // aliases wqkvb (used after GEMM1)
  // split-K partials live in the free tail of the wqkv region (after GEMM1):
  float* pk = (float*)(ws + OFF_W + 33554432ULL);  // 2 x 32MB
  __bf16* qkvb = (__bf16*)(ws + OFF_QKV);
  __bf16* ctxb = qkvb;                  // aliases qkv (used after rope)
  __bf16* Qb = (__bf16*)(ws + OFF_Q);
  __bf16* Kb = (__bf16*)(ws + OFF_K);
  _Float16* Vtb = (_Float16*)(ws + OFF_V);

  cvt_f32_bf16_kernel<<<(S_LEN * HID) / 4 / 256, 256, 0, stream>>>(
      hs, hsb, S_LEN * HID / 4);
  cvt_f32_bf16_kernel<<<(3 * HID * HID) / 4 / 256, 256, 0, stream>>>(
      Wqkv, wqkvb, 3 * HID * HID / 4);

  // GEMM1: [2048,4096] x [12288,4096]^T -> bf16 qkv. 8x48 tiles of 256^2.
  gemm256_kernel<1><<<8 * 48, 512, 0, stream>>>(hsb, wqkvb, bqkv, qkvb, S_LEN,
                                                3 * HID, HID, HID, 8, 1);

  cvt_f32_bf16_kernel<<<(HID * HID) / 4 / 256, 256, 0, stream>>>(
      Wd, wdb, HID * HID / 4);

  rope_kernel<<<NHEAD * (S_LEN / 64), 256, 0, stream>>>(qkvb, pos_ids, Qb, Kb,
                                                        Vtb);

  attn_kernel<<<NHEAD * (S_LEN / 128), 256, 0, stream>>>(Qb, Kb, Vtb, ctxb);

  // GEMM2 split-K=2: 256 blocks (1/CU), f32 partials, then reduce + bias.
  gemm256_kernel<2><<<2 * 8 * 16, 512, 0, stream>>>(ctxb, wdb, bd, pk, S_LEN,
                                                    HID, HID, HID / 2, 8, 2);
  reduce_addbias_kernel<<<(S_LEN * HID) / 4 / 256, 256, 0, stream>>>(
      pk, pk + (size_t)S_LEN * HID, bd, out);
}